// Round 1
// baseline (1470.681 us; speedup 1.0000x reference)
//
#include <hip/hip_runtime.h>
#include <hip/hip_bf16.h>

#define BB 8
#define TT 168
#define NN 425
#define EE 2048
#define II 128
#define HH 256
#define F1 10
#define F2 32
#define BT (BB*TT)       // 1344
#define K2 (NN*F2)       // 13600
#define N2 (2*NN)        // 850

__device__ __forceinline__ float relu_(float x){ return fmaxf(x, 0.f); }
__device__ __forceinline__ float sigmoid_(float x){ return 1.f/(1.f + expf(-x)); }
__device__ __forceinline__ float bf2f_(unsigned short u){ return __uint_as_float(((unsigned)u) << 16); }

// ---------------- GCN: two layers fused, one block per (b,t) graph ----------
__global__ __launch_bounds__(256) void gcn_kernel(
    const float* __restrict__ nf, const int* __restrict__ esrc,
    const int* __restrict__ edst, const float* __restrict__ ew,
    const float* __restrict__ Wg1, const float* __restrict__ bg1,
    const float* __restrict__ Wg2, const float* __restrict__ bg2,
    __hip_bfloat16* __restrict__ x2g)
{
    __shared__ float xs[NN];
    __shared__ float dinv[NN];     // holds deg first, then 1/sqrt(deg)
    __shared__ float agg1[NN];
    __shared__ float nrm[EE];
    __shared__ float x1[NN*F1];
    __shared__ float agg2[NN*F1];
    __shared__ float wg1s[F1], bg1s[F1], wg2s[F1*F2], bg2s[F2];

    const int bt = blockIdx.x, tid = threadIdx.x;
    const long eb = (long)bt * EE;

    for (int v = tid; v < NN; v += 256) {
        xs[v] = nf[(long)bt*NN + v];
        dinv[v] = 1.0f;            // self-loop weight
        agg1[v] = 0.f;
    }
    for (int i = tid; i < NN*F1; i += 256) agg2[i] = 0.f;
    if (tid < F1) { wg1s[tid] = Wg1[tid]; bg1s[tid] = bg1[tid]; }
    if (tid < F2) bg2s[tid] = bg2[tid];
    for (int i = tid; i < F1*F2; i += 256) wg2s[i] = Wg2[i];
    __syncthreads();

    for (int e = tid; e < EE; e += 256)
        atomicAdd(&dinv[edst[eb+e]], ew[eb+e]);
    __syncthreads();
    for (int v = tid; v < NN; v += 256) {
        float dg = dinv[v];
        dinv[v] = dg > 0.f ? 1.0f / sqrtf(fmaxf(dg, 1e-12f)) : 0.f;
    }
    __syncthreads();

    for (int e = tid; e < EE; e += 256) {
        int s = esrc[eb+e], d = edst[eb+e];
        float nm = dinv[s] * ew[eb+e] * dinv[d];
        nrm[e] = nm;
        atomicAdd(&agg1[d], nm * xs[s]);
    }
    __syncthreads();
    for (int v = tid; v < NN; v += 256) agg1[v] += dinv[v]*dinv[v]*xs[v];
    __syncthreads();
    for (int i = tid; i < NN*F1; i += 256) {
        int v = i / F1, f = i - v*F1;
        x1[i] = relu_(agg1[v] * wg1s[f] + bg1s[f]);
    }
    __syncthreads();

    for (int e = tid; e < EE; e += 256) {
        int s = esrc[eb+e], d = edst[eb+e];
        float nm = nrm[e];
        #pragma unroll
        for (int f = 0; f < F1; ++f)
            atomicAdd(&agg2[d*F1+f], nm * x1[s*F1+f]);
    }
    __syncthreads();
    for (int i = tid; i < NN*F1; i += 256) {
        int v = i / F1;
        agg2[i] += dinv[v]*dinv[v]*x1[i];
    }
    __syncthreads();

    for (int i = tid; i < NN*F2; i += 256) {
        int v = i >> 5, k = i & 31;
        float o = bg2s[k];
        #pragma unroll
        for (int f = 0; f < F1; ++f) o += agg2[v*F1+f] * wg2s[f*F2+k];
        x2g[(long)bt*K2 + i] = __float2bfloat16(relu_(o));
    }
}

// ---------------- split-K fp32 GEMM: g_pre += x2 @ Wgfc ---------------------
#define GMT 64
#define GKS 16
#define GKC 800
__global__ __launch_bounds__(256) void gemm_kernel(
    const __hip_bfloat16* __restrict__ A, const float* __restrict__ Bw,
    float* __restrict__ C)
{
    __shared__ __align__(16) float As[GKS][GMT];   // [k][row]
    __shared__ __align__(16) float Bs[GKS][II];    // [k][col]
    const int tid = threadIdx.x;
    const int row0 = blockIdx.x * GMT;
    const int kbase = blockIdx.y * GKC;

    const int lr = tid >> 2, lk0 = (tid & 3) * 4;
    const int bk = tid >> 4, bc = (tid & 15) * 8;
    const int r0 = (tid >> 5) << 3;
    const int c0 = (tid & 31) << 2;

    float acc[8][4];
    #pragma unroll
    for (int x = 0; x < 8; ++x)
        #pragma unroll
        for (int y = 0; y < 4; ++y) acc[x][y] = 0.f;

    for (int ks = 0; ks < GKC; ks += GKS) {
        const ushort* ap = (const ushort*)A + (long)(row0+lr)*K2 + kbase + ks + lk0;
        ushort4 av = *(const ushort4*)ap;
        As[lk0+0][lr] = bf2f_(av.x);
        As[lk0+1][lr] = bf2f_(av.y);
        As[lk0+2][lr] = bf2f_(av.z);
        As[lk0+3][lr] = bf2f_(av.w);
        const float* bp = Bw + (long)(kbase+ks+bk)*II + bc;
        *(float4*)&Bs[bk][bc]   = *(const float4*)bp;
        *(float4*)&Bs[bk][bc+4] = *(const float4*)(bp+4);
        __syncthreads();
        #pragma unroll
        for (int kk = 0; kk < GKS; ++kk) {
            float4 a0 = *(const float4*)&As[kk][r0];
            float4 a1 = *(const float4*)&As[kk][r0+4];
            float4 bv = *(const float4*)&Bs[kk][c0];
            float a[8] = {a0.x,a0.y,a0.z,a0.w,a1.x,a1.y,a1.z,a1.w};
            float b[4] = {bv.x,bv.y,bv.z,bv.w};
            #pragma unroll
            for (int x = 0; x < 8; ++x)
                #pragma unroll
                for (int y = 0; y < 4; ++y) acc[x][y] += a[x]*b[y];
        }
        __syncthreads();
    }
    #pragma unroll
    for (int x = 0; x < 8; ++x)
        #pragma unroll
        for (int y = 0; y < 4; ++y)
            atomicAdd(&C[(long)(row0+r0+x)*II + c0 + y], acc[x][y]);
}

// ---------------- infect & temp MLP branches (16 rows per block) ------------
__global__ __launch_bounds__(256) void branches_kernel(
    const float* __restrict__ infect, const float* __restrict__ temp,
    const float* __restrict__ Wi1, const float* __restrict__ bi1,
    const float* __restrict__ Wi2, const float* __restrict__ bi2,
    const float* __restrict__ Wi3, const float* __restrict__ bi3,
    const float* __restrict__ Wi4, const float* __restrict__ bi4,
    const float* __restrict__ Wt1, const float* __restrict__ bt1,
    const float* __restrict__ Wt2, const float* __restrict__ bt2,
    float* __restrict__ infout, float* __restrict__ tpout)
{
    __shared__ float inA[16*25], inT[16*13];
    __shared__ float bufA[16*II], bufB[16*II];
    const int r0 = blockIdx.x * 16, tid = threadIdx.x;

    for (int i = tid; i < 16*25; i += 256) { int r=i/25,k=i-r*25; inA[i] = infect[(long)(r0+r)*25+k]; }
    for (int i = tid; i < 16*13; i += 256) { int r=i/13,k=i-r*13; inT[i] = temp[(long)(r0+r)*13+k]; }
    __syncthreads();
    for (int i = tid; i < 16*II; i += 256) { int r=i>>7,u=i&127; float o=bi1[u];
        for (int k=0;k<25;++k) o += inA[r*25+k]*Wi1[k*II+u];
        bufA[i]=relu_(o); }
    __syncthreads();
    for (int i = tid; i < 16*II; i += 256) { int r=i>>7,u=i&127; float o=bi2[u];
        for (int k=0;k<II;++k) o += bufA[r*II+k]*Wi2[k*II+u];
        bufB[i]=relu_(o); }
    __syncthreads();
    for (int i = tid; i < 16*64; i += 256) { int r=i>>6,u=i&63; float o=bi3[u];
        for (int k=0;k<II;++k) o += bufB[r*II+k]*Wi3[k*64+u];
        bufA[r*64+u]=relu_(o); }
    __syncthreads();
    for (int i = tid; i < 16*II; i += 256) { int r=i>>7,u=i&127; float o=bi4[u];
        for (int k=0;k<64;++k) o += bufA[r*64+k]*Wi4[k*II+u];
        infout[(long)(r0+r)*II+u]=relu_(o); }
    for (int i = tid; i < 16*64; i += 256) { int r=i>>6,u=i&63; float o=bt1[u];
        for (int k=0;k<13;++k) o += inT[r*13+k]*Wt1[k*64+u];
        bufB[r*64+u]=relu_(o); }
    __syncthreads();
    for (int i = tid; i < 16*II; i += 256) { int r=i>>7,u=i&127; float o=bt2[u];
        for (int k=0;k<64;++k) o += bufB[r*64+k]*Wt2[k*II+u];
        tpout[(long)(r0+r)*II+u]=relu_(o); }
}

// ---------------- li = relu(cat@Wcat+bcat); xg = li@Wih^T + bih + bhh -------
__global__ __launch_bounds__(256) void li_xg_kernel(
    const float* __restrict__ g_pre, const float* __restrict__ bgfc,
    const float* __restrict__ infb, const float* __restrict__ tpb,
    const float* __restrict__ Wcat, const float* __restrict__ bcat,
    const float* __restrict__ Wih, const float* __restrict__ bih,
    const float* __restrict__ bhh, float* __restrict__ xg)
{
    __shared__ float cat[16*384];
    __shared__ __align__(16) float li[16*II];
    const int r0 = blockIdx.x * 16, tid = threadIdx.x;

    for (int i = tid; i < 16*II; i += 256) {
        int r = i>>7, u = i&127;
        cat[r*384 + u]       = relu_(g_pre[(long)(r0+r)*II+u] + bgfc[u]);
        cat[r*384 + 128 + u] = infb[(long)(r0+r)*II+u];
        cat[r*384 + 256 + u] = tpb[(long)(r0+r)*II+u];
    }
    __syncthreads();
    {
        int u = tid & 127, rh = tid >> 7;
        float acc[8];
        #pragma unroll
        for (int x = 0; x < 8; ++x) acc[x] = bcat[u];
        for (int k = 0; k < 384; ++k) {
            float w = Wcat[k*II+u];
            #pragma unroll
            for (int x = 0; x < 8; ++x) acc[x] += cat[(rh*8+x)*384 + k] * w;
        }
        #pragma unroll
        for (int x = 0; x < 8; ++x) li[(rh*8+x)*II + u] = relu_(acc[x]);
    }
    __syncthreads();
    for (int jj = 0; jj < 4; ++jj) {
        int j = tid + jj*256;
        float bb = bih[j] + bhh[j];
        float acc[16];
        #pragma unroll
        for (int r = 0; r < 16; ++r) acc[r] = bb;
        for (int k4 = 0; k4 < 32; ++k4) {
            float4 wv = *(const float4*)&Wih[(long)j*II + k4*4];
            #pragma unroll
            for (int r = 0; r < 16; ++r) {
                float4 lv = *(const float4*)&li[r*II + k4*4];
                acc[r] += wv.x*lv.x + wv.y*lv.y + wv.z*lv.z + wv.w*lv.w;
            }
        }
        #pragma unroll
        for (int r = 0; r < 16; ++r) xg[(long)(r0+r)*1024 + j] = acc[r];
    }
}

// ---------------- persistent LSTM: 4 blocks/batch, spin barrier -------------
__global__ __launch_bounds__(512) void lstm_kernel(
    const float* __restrict__ xg, const float* __restrict__ Whh,
    const float* __restrict__ h0, const float* __restrict__ c0,
    float* __restrict__ hbuf, unsigned int* __restrict__ cnt)
{
    const int tid = threadIdx.x;
    const int b = blockIdx.x >> 2;
    const int s = blockIdx.x & 3;
    const int u0 = s * 64;
    const int r = tid >> 1;
    const int half = tid & 1;
    const int gate = r >> 6, ul = r & 63;
    const int grow = gate*HH + u0 + ul;

    __shared__ __align__(16) float hlds[HH];
    __shared__ float gbuf[256];

    float4 w[32];
    const float4* wp = (const float4*)(Whh + (long)grow*HH + half*128);
    #pragma unroll
    for (int k = 0; k < 32; ++k) w[k] = wp[k];

    for (int i = tid; i < HH; i += 512) hlds[i] = h0[b*HH + i];
    float c = 0.f;
    if (tid < 64) c = c0[b*HH + u0 + tid];
    __syncthreads();

    #pragma unroll 1
    for (int t = 0; t < TT; ++t) {
        const float4* h4 = (const float4*)hlds + half*32;
        float p = 0.f;
        #pragma unroll
        for (int k = 0; k < 32; ++k) {
            float4 hv = h4[k];
            p += w[k].x*hv.x + w[k].y*hv.y + w[k].z*hv.z + w[k].w*hv.w;
        }
        p += __shfl_xor(p, 1);
        if (half == 0)
            gbuf[r] = p + xg[((long)b*TT + t)*1024 + grow];
        __syncthreads();
        if (tid < 64) {
            float gi = gbuf[tid], gf = gbuf[64+tid], gg = gbuf[128+tid], go = gbuf[192+tid];
            c = sigmoid_(gf)*c + sigmoid_(gi)*tanhf(gg);
            float hn = sigmoid_(go)*tanhf(c);
            __hip_atomic_store(&hbuf[(((t+1)&1)*BB + b)*HH + u0 + tid], hn,
                               __ATOMIC_RELAXED, __HIP_MEMORY_SCOPE_AGENT);
        }
        __threadfence();
        __syncthreads();
        if (tid == 0) {
            __hip_atomic_fetch_add(&cnt[b], 1u, __ATOMIC_RELEASE, __HIP_MEMORY_SCOPE_AGENT);
            unsigned target = 4u*(t+1);
            while (__hip_atomic_load(&cnt[b], __ATOMIC_ACQUIRE, __HIP_MEMORY_SCOPE_AGENT) < target)
                __builtin_amdgcn_s_sleep(2);
        }
        __syncthreads();
        if (t + 1 < TT) {
            for (int i = tid; i < HH; i += 512)
                hlds[i] = __hip_atomic_load(&hbuf[(((t+1)&1)*BB + b)*HH + i],
                                            __ATOMIC_RELAXED, __HIP_MEMORY_SCOPE_AGENT);
            __syncthreads();
        }
    }
}

// ---------------- final FC: out = relu(relu(h_T) @ Wfc + bfc) ---------------
__global__ __launch_bounds__(256) void final_fc_kernel(
    const float* __restrict__ hbuf, const float* __restrict__ Wfc,
    const float* __restrict__ bfc, float* __restrict__ out)
{
    int idx = blockIdx.x*256 + threadIdx.x;
    if (idx >= BB*N2) return;
    int b = idx / N2, j = idx - b*N2;
    const float* h = hbuf + b*HH;     // T=168 even -> h_T in buffer 0
    float o = bfc[j];
    for (int k = 0; k < HH; ++k) o += fmaxf(h[k], 0.f) * Wfc[(long)k*N2 + j];
    out[idx] = relu_(o);
}

extern "C" void kernel_launch(void* const* d_in, const int* in_sizes, int n_in,
                              void* d_out, int out_size, void* d_ws, size_t ws_size,
                              hipStream_t stream) {
    const float* nf     = (const float*)d_in[0];
    const int*   esrc   = (const int*)d_in[1];
    const int*   edst   = (const int*)d_in[2];
    const float* ew     = (const float*)d_in[3];
    const float* infect = (const float*)d_in[4];
    const float* temp   = (const float*)d_in[5];
    const float* h0     = (const float*)d_in[6];
    const float* c0     = (const float*)d_in[7];
    const float* Wg1    = (const float*)d_in[8];
    const float* bg1    = (const float*)d_in[9];
    const float* Wg2    = (const float*)d_in[10];
    const float* bg2    = (const float*)d_in[11];
    const float* Wgfc   = (const float*)d_in[12];
    const float* bgfc   = (const float*)d_in[13];
    const float* Wi1    = (const float*)d_in[14];
    const float* bi1    = (const float*)d_in[15];
    const float* Wi2    = (const float*)d_in[16];
    const float* bi2    = (const float*)d_in[17];
    const float* Wi3    = (const float*)d_in[18];
    const float* bi3    = (const float*)d_in[19];
    const float* Wi4    = (const float*)d_in[20];
    const float* bi4    = (const float*)d_in[21];
    const float* Wt1    = (const float*)d_in[22];
    const float* bt1    = (const float*)d_in[23];
    const float* Wt2    = (const float*)d_in[24];
    const float* bt2    = (const float*)d_in[25];
    const float* Wcat   = (const float*)d_in[26];
    const float* bcat   = (const float*)d_in[27];
    const float* Wih    = (const float*)d_in[28];
    const float* Whh    = (const float*)d_in[29];
    const float* bih    = (const float*)d_in[30];
    const float* bhh    = (const float*)d_in[31];
    const float* Wfc    = (const float*)d_in[32];
    const float* bfc    = (const float*)d_in[33];

    char* ws = (char*)d_ws;
    size_t off = 0;
    __hip_bfloat16* x2g = (__hip_bfloat16*)(ws + off); off += (size_t)BT*K2*2;
    float* g_pre = (float*)(ws + off); off += (size_t)BT*II*4;
    float* infb  = (float*)(ws + off); off += (size_t)BT*II*4;
    float* tpb   = (float*)(ws + off); off += (size_t)BT*II*4;
    float* xg    = (float*)(ws + off); off += (size_t)BT*1024*4;
    float* hbuf  = (float*)(ws + off); off += (size_t)2*BB*HH*4;
    unsigned int* cnt = (unsigned int*)(ws + off); off += 256;

    hipMemsetAsync(g_pre, 0, (size_t)BT*II*4, stream);
    hipMemsetAsync(cnt, 0, 256, stream);

    gcn_kernel<<<BT, 256, 0, stream>>>(nf, esrc, edst, ew, Wg1, bg1, Wg2, bg2, x2g);
    branches_kernel<<<BT/16, 256, 0, stream>>>(infect, temp, Wi1, bi1, Wi2, bi2,
                                               Wi3, bi3, Wi4, bi4, Wt1, bt1, Wt2, bt2,
                                               infb, tpb);
    gemm_kernel<<<dim3(BT/GMT, K2/GKC), 256, 0, stream>>>(x2g, Wgfc, g_pre);
    li_xg_kernel<<<BT/16, 256, 0, stream>>>(g_pre, bgfc, infb, tpb, Wcat, bcat,
                                            Wih, bih, bhh, xg);
    lstm_kernel<<<BB*4, 512, 0, stream>>>(xg, Whh, h0, c0, hbuf, cnt);
    final_fc_kernel<<<(BB*N2 + 255)/256, 256, 0, stream>>>(hbuf, Wfc, bfc, (float*)d_out);
}